// Round 2
// baseline (258.921 us; speedup 1.0000x reference)
//
#include <hip/hip_runtime.h>

// HyperbolicMultiheadAttention — fully fused persistent kernel.
//
// Math: w = exp(-arccosh(max(cos_sim,1))) == 1 identically, so
//   d_out[b,s,:] = ((sum_s value[b,s,:]) @ w_v^T + S*b_v) @ w_o^T + b_o
// (constant over s per batch). One kernel, 256 blocks (1/CU, co-resident),
// grid barriers via device-scope atomics. Barrier counters zeroed by a
// hipMemsetAsync before launch (d_ws is re-poisoned to 0xAA each call).

constexpr int B = 4;
constexpr int S = 2048;      // rows per batch
constexpr int D = 1024;      // model dim
constexpr int NBLK = 256;    // one block per CU; co-residency guaranteed
constexpr int NTHR = 256;

// ws float-offset layout:
//   [0..63]                ctrl (unsigned): ctr at 0..2, rel at 8..10
//   [64 .. 64+65536)       partialv: [16 schunk][4 b][1024 d] floats
//   [.. +4096)             attn[4][1024]
//   [.. +4096)             fin[4][1024]
constexpr int WS_PARTIAL = 64;
constexpr int WS_ATTN = WS_PARTIAL + 16 * 4 * 1024;
constexpr int WS_FIN = WS_ATTN + 4096;

__device__ __forceinline__ void gbarrier(unsigned* ctr, unsigned* rel) {
  __threadfence();
  __syncthreads();
  if (threadIdx.x == 0) {
    unsigned prev = __hip_atomic_fetch_add(ctr, 1u, __ATOMIC_ACQ_REL,
                                           __HIP_MEMORY_SCOPE_AGENT);
    if (prev == (unsigned)(NBLK - 1)) {
      __hip_atomic_store(rel, 1u, __ATOMIC_RELEASE, __HIP_MEMORY_SCOPE_AGENT);
    } else {
      int spins = 0;
      while (__hip_atomic_load(rel, __ATOMIC_ACQUIRE,
                               __HIP_MEMORY_SCOPE_AGENT) == 0u) {
        __builtin_amdgcn_s_sleep(2);
        if (++spins > 30000000) break;  // failsafe: never hang the bench
      }
    }
  }
  __syncthreads();
}

__global__ __launch_bounds__(NTHR, 2) void fused_hyp_attn(
    const float4* __restrict__ value4, const float4* __restrict__ wv4,
    const float* __restrict__ bv, const float4* __restrict__ wo4,
    const float* __restrict__ bo, float4* __restrict__ out4,
    float* __restrict__ ws) {
  const int tid = threadIdx.x;
  const int wave = tid >> 6;
  const int lane = tid & 63;
  const int x = blockIdx.x;  // 0..255

  unsigned* ctrl = (unsigned*)ws;
  float* partialv = ws + WS_PARTIAL;              // [c][b][d] floats
  float4* partialv4 = (float4*)partialv;
  float* attn = ws + WS_ATTN;
  float* fin = ws + WS_FIN;
  const float4* fin4 = (const float4*)fin;

  __shared__ float lds[4 * 1024];  // 16 KB
  float4* lds4 = (float4*)lds;

  // ---- Phase 1: column-sum of value over s (partial, per s-chunk) ----
  {
    const int b = x & 3;
    const int dchunk = (x >> 2) & 3;   // 4 chunks of 256 floats (64 float4)
    const int schunk = x >> 4;         // 16 chunks of 128 rows
    const int d4 = dchunk * 64 + lane;
    const int row0 = schunk * 128 + wave * 32;
    const float4* base = value4 + (size_t)(b * S + row0) * (D / 4) + d4;
    float4 acc = {0.f, 0.f, 0.f, 0.f};
#pragma unroll
    for (int i = 0; i < 32; ++i) {
      float4 v = base[(size_t)i * (D / 4)];
      acc.x += v.x; acc.y += v.y; acc.z += v.z; acc.w += v.w;
    }
    lds4[wave * 64 + lane] = acc;
    __syncthreads();
    if (wave == 0) {
      float4 a0 = lds4[lane], a1 = lds4[64 + lane];
      float4 a2 = lds4[128 + lane], a3 = lds4[192 + lane];
      float4 s4;
      s4.x = (a0.x + a1.x) + (a2.x + a3.x);
      s4.y = (a0.y + a1.y) + (a2.y + a3.y);
      s4.z = (a0.z + a1.z) + (a2.z + a3.z);
      s4.w = (a0.w + a1.w) + (a2.w + a3.w);
      partialv4[(schunk * 4 + b) * (D / 4) + d4] = s4;
    }
  }
  gbarrier(&ctrl[0], &ctrl[8]);

  // ---- Phase 2: reduce partials -> LDS vsum[4][1024]; gemv1 (w_v) ----
  {
#pragma unroll
    for (int i = 0; i < 16; ++i) {
      const int idx = tid + 256 * i;  // idx = b*1024 + d
      float s = 0.f;
#pragma unroll
      for (int c = 0; c < 16; ++c) s += partialv[c * 4096 + idx];
      lds[idx] = s;
    }
    __syncthreads();
    const int j = x * 4 + wave;  // each wave computes one output feature j
    const float4* wrow = wv4 + (size_t)j * (D / 4);
    float acc[4] = {0.f, 0.f, 0.f, 0.f};
#pragma unroll
    for (int it = 0; it < 4; ++it) {
      float4 w = wrow[it * 64 + lane];
#pragma unroll
      for (int b = 0; b < 4; ++b) {
        float4 xv = lds4[b * 256 + it * 64 + lane];
        acc[b] += w.x * xv.x + w.y * xv.y + w.z * xv.z + w.w * xv.w;
      }
    }
#pragma unroll
    for (int off = 32; off; off >>= 1)
#pragma unroll
      for (int b = 0; b < 4; ++b) acc[b] += __shfl_xor(acc[b], off, 64);
    if (lane == 0) {
      const float bias = (float)S * bv[j];
#pragma unroll
      for (int b = 0; b < 4; ++b) attn[b * D + j] = acc[b] + bias;
    }
  }
  gbarrier(&ctrl[1], &ctrl[9]);

  // ---- Phase 3: gemv2 (w_o) ----
  {
#pragma unroll
    for (int i = 0; i < 16; ++i) {
      const int idx = tid + 256 * i;
      lds[idx] = attn[idx];
    }
    __syncthreads();
    const int j = x * 4 + wave;
    const float4* wrow = wo4 + (size_t)j * (D / 4);
    float acc[4] = {0.f, 0.f, 0.f, 0.f};
#pragma unroll
    for (int it = 0; it < 4; ++it) {
      float4 w = wrow[it * 64 + lane];
#pragma unroll
      for (int b = 0; b < 4; ++b) {
        float4 xv = lds4[b * 256 + it * 64 + lane];
        acc[b] += w.x * xv.x + w.y * xv.y + w.z * xv.z + w.w * xv.w;
      }
    }
#pragma unroll
    for (int off = 32; off; off >>= 1)
#pragma unroll
      for (int b = 0; b < 4; ++b) acc[b] += __shfl_xor(acc[b], off, 64);
    if (lane == 0) {
      const float bias = bo[j];
#pragma unroll
      for (int b = 0; b < 4; ++b) fin[b * D + j] = acc[b] + bias;
    }
  }
  gbarrier(&ctrl[2], &ctrl[10]);

  // ---- Phase 4: broadcast fin[b,:] over all s ----
  {
    const int b = x & 3;
    const int schunk = x >> 2;  // 64 chunks of 32 rows
    const float4 val = fin4[b * (D / 4) + tid];
    const size_t rowbase = (size_t)(b * S + schunk * 32) * (D / 4) + tid;
#pragma unroll
    for (int r = 0; r < 32; ++r) out4[rowbase + (size_t)r * (D / 4)] = val;
  }
}

extern "C" void kernel_launch(void* const* d_in, const int* in_sizes, int n_in,
                              void* d_out, int out_size, void* d_ws, size_t ws_size,
                              hipStream_t stream) {
  // inputs: query,key,value,w_q,b_q,w_k,b_k,w_v,b_v,w_o,b_o
  const float4* value4 = (const float4*)d_in[2];
  const float4* wv4 = (const float4*)d_in[7];
  const float* bv = (const float*)d_in[8];
  const float4* wo4 = (const float4*)d_in[9];
  const float* bo = (const float*)d_in[10];

  // zero the barrier counters (d_ws is poisoned to 0xAA before every call)
  hipMemsetAsync(d_ws, 0, 256, stream);

  fused_hyp_attn<<<NBLK, NTHR, 0, stream>>>(value4, wv4, bv, wo4, bo,
                                            (float4*)d_out, (float*)d_ws);
}

// Round 4
// 170.978 us; speedup vs baseline: 1.5144x; 1.5144x over previous
//
#include <hip/hip_runtime.h>

// HyperbolicMultiheadAttention — fused persistent kernel, v2.1.
//
// Math: w = exp(-arccosh(max(cos_sim,1))) == 1 identically (cosine of unit
// vectors <= 1), so
//   d_out[b,s,:] = ((sum_s value[b,s,:]) @ w_v^T + S*b_v) @ w_o^T + b_o
// constant over s per batch. Q/K projections are dead code.
//
// v2 fixes the v1 barrier: v1 spun on an ACQUIRE agent-scope atomic load,
// which emits a cache-invalidate per iteration on multi-XCD gfx950 ->
// continuous L2 thrash from 255 CUs (kernel ran at 403 GB/s, VALUBusy 1%).
// Now: RELAXED spin + one release fence before arrival + one acquire fence
// after release. v2.1: __hip_atomic_fence doesn't exist in these headers;
// use __builtin_amdgcn_fence(order, "agent") instead.

constexpr int B = 4;
constexpr int S = 2048;
constexpr int D = 1024;
constexpr int D4 = D / 4;    // 256
constexpr int NBLK = 256;    // one block per CU
constexpr int NTHR = 512;    // 8 waves

// ws float-offset layout:
//   [0..255]      ctrl (uint): ctr_i at 32*i (i=0..2), rel_i at 96+32*i
//   [256..4351]   vsum[4][1024]   (memset to 0 with ctrl)
//   [4352..8447]  attn[4][1024]
//   [8448..12543] fin[4][1024]
constexpr int WS_VSUM = 256;
constexpr int WS_ATTN = WS_VSUM + B * D;
constexpr int WS_FIN = WS_ATTN + B * D;

__device__ __forceinline__ void gbarrier(unsigned* ctr, unsigned* rel) {
  __syncthreads();
  if (threadIdx.x == 0) {
    // one writeback of this XCD's dirty lines (covers the whole block's
    // stores; __syncthreads above ordered them before this fence)
    __builtin_amdgcn_fence(__ATOMIC_RELEASE, "agent");
    unsigned prev = __hip_atomic_fetch_add(ctr, 1u, __ATOMIC_RELAXED,
                                           __HIP_MEMORY_SCOPE_AGENT);
    if (prev == (unsigned)(NBLK - 1)) {
      __hip_atomic_store(rel, 1u, __ATOMIC_RELAXED, __HIP_MEMORY_SCOPE_AGENT);
    } else {
      int spins = 0;
      while (__hip_atomic_load(rel, __ATOMIC_RELAXED,
                               __HIP_MEMORY_SCOPE_AGENT) == 0u) {
        __builtin_amdgcn_s_sleep(8);
        if (++spins > 2000000) break;  // failsafe: never hang the bench
      }
    }
    // one invalidate so subsequent plain loads see other XCDs' writes
    __builtin_amdgcn_fence(__ATOMIC_ACQUIRE, "agent");
  }
  __syncthreads();
}

__global__ __launch_bounds__(NTHR, 2) void fused_hyp_attn(
    const float4* __restrict__ value4, const float4* __restrict__ wv4,
    const float* __restrict__ bv, const float4* __restrict__ wo4,
    const float* __restrict__ bo, float4* __restrict__ out4,
    float* __restrict__ ws) {
  const int tid = threadIdx.x;
  const int x = blockIdx.x;  // 0..255
  const int wave = tid >> 6;
  const int lane = tid & 63;

  unsigned* ctrl = (unsigned*)ws;
  float* vsum = ws + WS_VSUM;
  float* attn = ws + WS_ATTN;
  float* fin = ws + WS_FIN;

  __shared__ float lds[4096 + 64];  // ~16.3 KB
  float4* lds4 = (float4*)lds;
  float* lds_p = lds + 4096;

  // ---- Phase 1: colsum of value over s, atomicAdd into vsum ----
  {
    const int b = x & 3;
    const int dc = (x >> 2) & 7;  // 8 col-chunks of 32 float4 (512 B/row)
    const int sc = x >> 5;        // 8 row-chunks of 256 rows
    const int c4 = tid & 31;
    const int rg = tid >> 5;      // 16 row-groups of 16 rows
    const float4* base =
        value4 + ((size_t)(b * S + sc * 256 + rg * 16)) * D4 + dc * 32 + c4;
    float4 a0 = {0.f, 0.f, 0.f, 0.f}, a1 = {0.f, 0.f, 0.f, 0.f};
#pragma unroll
    for (int i = 0; i < 8; ++i) {
      float4 v0 = base[(size_t)(2 * i) * D4];
      float4 v1 = base[(size_t)(2 * i + 1) * D4];
      a0.x += v0.x; a0.y += v0.y; a0.z += v0.z; a0.w += v0.w;
      a1.x += v1.x; a1.y += v1.y; a1.z += v1.z; a1.w += v1.w;
    }
    a0.x += a1.x; a0.y += a1.y; a0.z += a1.z; a0.w += a1.w;
    lds4[tid] = a0;  // [rg][c4]
    __syncthreads();
    if (tid < 32) {
      float4 s = lds4[tid];
#pragma unroll
      for (int r = 1; r < 16; ++r) {
        float4 v = lds4[r * 32 + tid];
        s.x += v.x; s.y += v.y; s.z += v.z; s.w += v.w;
      }
      float* vs = vsum + b * D + dc * 128 + tid * 4;
      atomicAdd(vs + 0, s.x);
      atomicAdd(vs + 1, s.y);
      atomicAdd(vs + 2, s.z);
      atomicAdd(vs + 3, s.w);
    }
  }
  gbarrier(&ctrl[0], &ctrl[96]);

  // ---- Phase 2: gemv1  attn = vsum @ w_v^T + S*b_v ----
  {
    const float4* vsum4 = (const float4*)vsum;
    lds4[tid] = vsum4[tid];
    lds4[tid + 512] = vsum4[tid + 512];
    __syncthreads();
    const int jj = wave & 3;     // which of this block's 4 output features
    const int h = wave >> 2;     // which half of D
    const int j = x * 4 + jj;
    const float4* wrow = wv4 + (size_t)j * D4 + h * 128;
    float acc[4] = {0.f, 0.f, 0.f, 0.f};
#pragma unroll
    for (int it = 0; it < 2; ++it) {
      float4 w = wrow[it * 64 + lane];
#pragma unroll
      for (int bb = 0; bb < 4; ++bb) {
        float4 xv = lds4[bb * 256 + h * 128 + it * 64 + lane];
        acc[bb] += w.x * xv.x + w.y * xv.y + w.z * xv.z + w.w * xv.w;
      }
    }
#pragma unroll
    for (int off = 32; off; off >>= 1)
#pragma unroll
      for (int bb = 0; bb < 4; ++bb) acc[bb] += __shfl_xor(acc[bb], off, 64);
    if (lane == 0) {
#pragma unroll
      for (int bb = 0; bb < 4; ++bb) lds_p[wave * 4 + bb] = acc[bb];
    }
    __syncthreads();
    if (tid < 16) {
      const int bb = tid & 3, jj2 = tid >> 2;
      const int j2 = x * 4 + jj2;
      float v = lds_p[jj2 * 4 + bb] + lds_p[(jj2 + 4) * 4 + bb];
      attn[bb * D + j2] = v + (float)S * bv[j2];
    }
  }
  gbarrier(&ctrl[32], &ctrl[128]);

  // ---- Phase 3: gemv2  fin = attn @ w_o^T + b_o ----
  {
    const float4* attn4 = (const float4*)attn;
    lds4[tid] = attn4[tid];
    lds4[tid + 512] = attn4[tid + 512];
    __syncthreads();
    const int jj = wave & 3;
    const int h = wave >> 2;
    const int j = x * 4 + jj;
    const float4* wrow = wo4 + (size_t)j * D4 + h * 128;
    float acc[4] = {0.f, 0.f, 0.f, 0.f};
#pragma unroll
    for (int it = 0; it < 2; ++it) {
      float4 w = wrow[it * 64 + lane];
#pragma unroll
      for (int bb = 0; bb < 4; ++bb) {
        float4 xv = lds4[bb * 256 + h * 128 + it * 64 + lane];
        acc[bb] += w.x * xv.x + w.y * xv.y + w.z * xv.z + w.w * xv.w;
      }
    }
#pragma unroll
    for (int off = 32; off; off >>= 1)
#pragma unroll
      for (int bb = 0; bb < 4; ++bb) acc[bb] += __shfl_xor(acc[bb], off, 64);
    if (lane == 0) {
#pragma unroll
      for (int bb = 0; bb < 4; ++bb) lds_p[wave * 4 + bb] = acc[bb];
    }
    __syncthreads();
    if (tid < 16) {
      const int bb = tid & 3, jj2 = tid >> 2;
      const int j2 = x * 4 + jj2;
      float v = lds_p[jj2 * 4 + bb] + lds_p[(jj2 + 4) * 4 + bb];
      fin[bb * D + j2] = v + bo[j2];
    }
  }
  gbarrier(&ctrl[64], &ctrl[160]);

  // ---- Phase 4: broadcast fin[b,:] over all s ----
  {
    const int b = x & 3;
    const int sch = x >> 2;    // 64 chunks of 32 rows
    const int dp = tid & 255;  // float4 column
    const int ro = tid >> 8;   // 0/1
    const float4 val = ((const float4*)fin)[b * D4 + dp];
    float4* obase = out4 + ((size_t)(b * S + sch * 32 + ro)) * D4 + dp;
#pragma unroll
    for (int i = 0; i < 16; ++i) obase[(size_t)(2 * i) * D4] = val;
  }
}

extern "C" void kernel_launch(void* const* d_in, const int* in_sizes, int n_in,
                              void* d_out, int out_size, void* d_ws, size_t ws_size,
                              hipStream_t stream) {
  // inputs: query,key,value,w_q,b_q,w_k,b_k,w_v,b_v,w_o,b_o
  const float4* value4 = (const float4*)d_in[2];
  const float4* wv4 = (const float4*)d_in[7];
  const float* bv = (const float*)d_in[8];
  const float4* wo4 = (const float4*)d_in[9];
  const float* bo = (const float*)d_in[10];

  // zero barrier counters + vsum (d_ws is poisoned to 0xAA before every call)
  (void)hipMemsetAsync(d_ws, 0, (size_t)(WS_VSUM + B * D) * sizeof(float),
                       stream);

  fused_hyp_attn<<<NBLK, NTHR, 0, stream>>>(value4, wv4, bv, wo4, bo,
                                            (float4*)d_out, (float*)d_ws);
}

// Round 5
// 156.387 us; speedup vs baseline: 1.6556x; 1.0933x over previous
//
#include <hip/hip_runtime.h>

// HyperbolicMultiheadAttention — multi-kernel pipeline, v3.
//
// Math: w = exp(-arccosh(max(cos_sim,1))) == 1 identically (cosine of unit
// vectors <= 1), so
//   d_out[b,s,:] = ((sum_s value[b,s,:]) @ w_v^T + S*b_v) @ w_o^T + b_o
// constant over s per batch. Q/K projections are dead code.
//
// v3: measured evidence (r4): software grid barriers cost ~10 us each
// (256 contended atomics on one line, serialized at the coherent point),
// while graph kernel-node boundaries cost ~2 us. So use the graph as the
// barrier: memset(16KB) -> colsum(atomic) -> gemv(w_v) -> gemv(w_o) ->
// broadcast. 64 MB compulsory HBM traffic ~= 10 us; everything else is
// node overhead.

constexpr int B = 4;
constexpr int S = 2048;
constexpr int D = 1024;
constexpr int D4 = D / 4;  // 256

// ws float layout: vsum[4][1024] @ 0 (memset to 0), attn @ 4096, fin @ 8192
constexpr int WS_VSUM = 0;
constexpr int WS_ATTN = 4096;
constexpr int WS_FIN = 8192;

// 256 blocks x 512 threads. Block (b, sc) sums 32 rows of value[b] and
// atomicAdds its 1024-float column-partial into vsum[b].
__global__ __launch_bounds__(512) void k_colsum(const float4* __restrict__ value4,
                                                float* __restrict__ vsum) {
  __shared__ float4 lds4[512];
  const int tid = threadIdx.x;
  const int b = blockIdx.x >> 6;       // 0..3
  const int sc = blockIdx.x & 63;      // 0..63 (32-row chunks)
  const int col4 = tid & 255;
  const int rg = tid >> 8;             // 0/1 (16-row halves)
  const float4* base =
      value4 + ((size_t)(b * S + sc * 32 + rg * 16)) * D4 + col4;
  float4 a = {0.f, 0.f, 0.f, 0.f};
#pragma unroll
  for (int i = 0; i < 16; ++i) {
    float4 v = base[(size_t)i * D4];
    a.x += v.x; a.y += v.y; a.z += v.z; a.w += v.w;
  }
  lds4[rg * 256 + col4] = a;
  __syncthreads();
  if (tid < 256) {
    float4 s0 = lds4[tid], s1 = lds4[256 + tid];
    float* vs = vsum + b * D + tid * 4;
    atomicAdd(vs + 0, s0.x + s1.x);
    atomicAdd(vs + 1, s0.y + s1.y);
    atomicAdd(vs + 2, s0.z + s1.z);
    atomicAdd(vs + 3, s0.w + s1.w);
  }
}

// y[b,j] = dot(x[b,:], w[j,:]) + bias_scale*bias[j], for all 4 b.
// 256 blocks x 256 threads; wave w of block x computes j = x*4+w.
__global__ __launch_bounds__(256) void k_gemv(const float* __restrict__ xin,
                                              const float4* __restrict__ w4,
                                              const float* __restrict__ bias,
                                              float bias_scale,
                                              float* __restrict__ y) {
  __shared__ float4 lds4[1024];  // xin: 4 x 1024 floats = 16 KB
  const int tid = threadIdx.x;
  const int wave = tid >> 6;
  const int lane = tid & 63;
  const float4* xin4 = (const float4*)xin;
#pragma unroll
  for (int i = 0; i < 4; ++i) lds4[tid + 256 * i] = xin4[tid + 256 * i];
  __syncthreads();
  const int j = blockIdx.x * 4 + wave;
  const float4* wrow = w4 + (size_t)j * D4;
  float acc[4] = {0.f, 0.f, 0.f, 0.f};
#pragma unroll
  for (int it = 0; it < 4; ++it) {
    float4 w = wrow[it * 64 + lane];
#pragma unroll
    for (int bb = 0; bb < 4; ++bb) {
      float4 xv = lds4[bb * 256 + it * 64 + lane];
      acc[bb] += w.x * xv.x + w.y * xv.y + w.z * xv.z + w.w * xv.w;
    }
  }
#pragma unroll
  for (int off = 32; off; off >>= 1)
#pragma unroll
    for (int bb = 0; bb < 4; ++bb) acc[bb] += __shfl_xor(acc[bb], off, 64);
  if (lane == 0) {
    const float bj = bias_scale * bias[j];
#pragma unroll
    for (int bb = 0; bb < 4; ++bb) y[bb * D + j] = acc[bb] + bj;
  }
}

// d_out[b,s,:] = fin[b,:] for all s. 256 blocks x 512 threads, full-row
// float4 writes (1 KB contiguous per wave).
__global__ __launch_bounds__(512) void k_bcast(const float* __restrict__ fin,
                                               float4* __restrict__ out4) {
  const int tid = threadIdx.x;
  const int b = blockIdx.x & 3;
  const int sch = blockIdx.x >> 2;  // 64 chunks of 32 rows
  const int dp = tid & 255;
  const int ro = tid >> 8;  // 0/1
  const float4 val = ((const float4*)fin)[b * D4 + dp];
  float4* obase = out4 + ((size_t)(b * S + sch * 32 + ro)) * D4 + dp;
#pragma unroll
  for (int i = 0; i < 16; ++i) obase[(size_t)(2 * i) * D4] = val;
}

extern "C" void kernel_launch(void* const* d_in, const int* in_sizes, int n_in,
                              void* d_out, int out_size, void* d_ws, size_t ws_size,
                              hipStream_t stream) {
  // inputs: query,key,value,w_q,b_q,w_k,b_k,w_v,b_v,w_o,b_o
  const float4* value4 = (const float4*)d_in[2];
  const float4* wv4 = (const float4*)d_in[7];
  const float* bv = (const float*)d_in[8];
  const float4* wo4 = (const float4*)d_in[9];
  const float* bo = (const float*)d_in[10];

  float* ws = (float*)d_ws;
  float* vsum = ws + WS_VSUM;
  float* attn = ws + WS_ATTN;
  float* fin = ws + WS_FIN;

  // zero vsum (d_ws is poisoned to 0xAA before every call)
  (void)hipMemsetAsync(vsum, 0, (size_t)B * D * sizeof(float), stream);

  k_colsum<<<256, 512, 0, stream>>>(value4, vsum);
  k_gemv<<<256, 256, 0, stream>>>(vsum, wv4, bv, (float)S, attn);
  k_gemv<<<256, 256, 0, stream>>>(attn, wo4, bo, 1.0f, fin);
  k_bcast<<<256, 512, 0, stream>>>(fin, (float4*)d_out);
}

// Round 6
// 148.157 us; speedup vs baseline: 1.7476x; 1.0555x over previous
//
#include <hip/hip_runtime.h>

// HyperbolicMultiheadAttention — multi-kernel pipeline, v4.
//
// Math: w = exp(-arccosh(max(cos_sim,1))) == 1 identically (cosine of unit
// vectors <= 1), so
//   d_out[b,s,:] = ((sum_s value[b,s,:]) @ w_v^T + S*b_v) @ w_o^T + b_o
// constant over s per batch. Q/K projections are dead code.
//
// Session evidence:
//  - software grid barriers: ~10 us each (contended atomics at coherent
//    point) -> use graph node boundaries (~2 us) as barriers instead (r4).
//  - atomicAdd colsum into 16 KB: ~+5 us serialization (r5) -> v4 uses a
//    small partial array (128 KB, L2-resident) + inline reduce in gemv1's
//    prologue. 4 nodes, no atomics, no memset, deterministic.

constexpr int B = 4;
constexpr int S = 2048;
constexpr int D = 1024;
constexpr int D4 = D / 4;  // 256

// ws float4 layout: partial[8][4][256] @ 0 (8 s-chunks x 4 b x 256 float4),
// attn[4][256] @ 8192, fin[4][256] @ 9216
constexpr int WSP_PART = 0;
constexpr int WSP_ATTN = 8192;
constexpr int WSP_FIN = 9216;

// 256 blocks = b(4) x sc(8 chunks of 256 rows) x dc(8 slices of 32 float4).
// Block sums its 256-row x 128-float tile; tree-reduce in LDS; one partial
// write. Reads 32 MB total, writes 128 KB.
__global__ __launch_bounds__(512) void k_colsum_partial(
    const float4* __restrict__ value4, float4* __restrict__ partial4) {
  __shared__ float4 lds4[512];
  const int tid = threadIdx.x;
  const int b = blockIdx.x >> 6;
  const int sc = (blockIdx.x >> 3) & 7;
  const int dc = blockIdx.x & 7;
  const int c4 = tid & 31;   // float4 col in slice
  const int rg = tid >> 5;   // 16 row-groups of 16 rows
  const float4* base =
      value4 + ((size_t)(b * S + sc * 256 + rg * 16)) * D4 + dc * 32 + c4;
  float4 a = {0.f, 0.f, 0.f, 0.f};
#pragma unroll
  for (int i = 0; i < 16; ++i) {
    float4 v = base[(size_t)i * D4];
    a.x += v.x; a.y += v.y; a.z += v.z; a.w += v.w;
  }
  lds4[tid] = a;
  __syncthreads();
#pragma unroll
  for (int step = 256; step >= 32; step >>= 1) {
    if (tid < step) {
      float4 o = lds4[tid + step];
      float4 m = lds4[tid];
      m.x += o.x; m.y += o.y; m.z += o.z; m.w += o.w;
      lds4[tid] = m;
    }
    __syncthreads();
  }
  if (tid < 32) {
    partial4[((sc * 4 + b) * 256) + dc * 32 + tid] = lds4[tid];
  }
}

// 256 blocks x 256 threads. Prologue: reduce the 8 partial chunks into LDS
// vsum[4][1024] (L2-resident reads). Then wave w computes feature
// j = blockIdx.x*4 + w for all 4 batches: attn[b,j] = dot(vsum[b], wv[j]) +
// S*bv[j].
__global__ __launch_bounds__(256) void k_gemv1(const float4* __restrict__ partial4,
                                               const float4* __restrict__ wv4,
                                               const float* __restrict__ bv,
                                               float* __restrict__ attn) {
  __shared__ float4 lds4[1024];  // vsum: [b][256 float4]
  const int tid = threadIdx.x;
  const int wave = tid >> 6;
  const int lane = tid & 63;
#pragma unroll
  for (int i = 0; i < 4; ++i) {
    const int idx = tid + 256 * i;  // idx = b*256 + col4
    float4 s = partial4[idx];
#pragma unroll
    for (int c = 1; c < 8; ++c) {
      float4 v = partial4[c * 1024 + idx];
      s.x += v.x; s.y += v.y; s.z += v.z; s.w += v.w;
    }
    lds4[idx] = s;
  }
  __syncthreads();
  const int j = blockIdx.x * 4 + wave;
  const float4* wrow = wv4 + (size_t)j * D4;
  float acc[4] = {0.f, 0.f, 0.f, 0.f};
#pragma unroll
  for (int it = 0; it < 4; ++it) {
    float4 w = wrow[it * 64 + lane];
#pragma unroll
    for (int bb = 0; bb < 4; ++bb) {
      float4 xv = lds4[bb * 256 + it * 64 + lane];
      acc[bb] += w.x * xv.x + w.y * xv.y + w.z * xv.z + w.w * xv.w;
    }
  }
#pragma unroll
  for (int off = 32; off; off >>= 1)
#pragma unroll
    for (int bb = 0; bb < 4; ++bb) acc[bb] += __shfl_xor(acc[bb], off, 64);
  if (lane == 0) {
    const float bj = (float)S * bv[j];
#pragma unroll
    for (int bb = 0; bb < 4; ++bb) attn[bb * D + j] = acc[bb] + bj;
  }
}

// Same shape as k_gemv1 but reads attn directly (16 KB, L2-resident).
__global__ __launch_bounds__(256) void k_gemv2(const float* __restrict__ attn,
                                               const float4* __restrict__ wo4,
                                               const float* __restrict__ bo,
                                               float* __restrict__ fin) {
  __shared__ float4 lds4[1024];
  const int tid = threadIdx.x;
  const int wave = tid >> 6;
  const int lane = tid & 63;
  const float4* attn4 = (const float4*)attn;
#pragma unroll
  for (int i = 0; i < 4; ++i) lds4[tid + 256 * i] = attn4[tid + 256 * i];
  __syncthreads();
  const int j = blockIdx.x * 4 + wave;
  const float4* wrow = wo4 + (size_t)j * D4;
  float acc[4] = {0.f, 0.f, 0.f, 0.f};
#pragma unroll
  for (int it = 0; it < 4; ++it) {
    float4 w = wrow[it * 64 + lane];
#pragma unroll
    for (int bb = 0; bb < 4; ++bb) {
      float4 xv = lds4[bb * 256 + it * 64 + lane];
      acc[bb] += w.x * xv.x + w.y * xv.y + w.z * xv.z + w.w * xv.w;
    }
  }
#pragma unroll
  for (int off = 32; off; off >>= 1)
#pragma unroll
    for (int bb = 0; bb < 4; ++bb) acc[bb] += __shfl_xor(acc[bb], off, 64);
  if (lane == 0) {
    const float bj = bo[j];
#pragma unroll
    for (int bb = 0; bb < 4; ++bb) fin[bb * D + j] = acc[bb] + bj;
  }
}

// d_out[b,s,:] = fin[b,:] for all s. 512 blocks x 512 threads; each block
// writes 16 rows (64 KB) with 1 KB-per-wave-instr contiguous float4 stores.
__global__ __launch_bounds__(512) void k_bcast(const float* __restrict__ fin,
                                               float4* __restrict__ out4) {
  const int tid = threadIdx.x;
  const int b = blockIdx.x & 3;
  const int sch = blockIdx.x >> 2;  // 128 chunks of 16 rows
  const int dp = tid & 255;
  const int ro = tid >> 8;  // 0/1
  const float4 val = ((const float4*)fin)[b * D4 + dp];
  float4* obase = out4 + ((size_t)(b * S + sch * 16 + ro)) * D4 + dp;
#pragma unroll
  for (int i = 0; i < 8; ++i) obase[(size_t)(2 * i) * D4] = val;
}

extern "C" void kernel_launch(void* const* d_in, const int* in_sizes, int n_in,
                              void* d_out, int out_size, void* d_ws, size_t ws_size,
                              hipStream_t stream) {
  // inputs: query,key,value,w_q,b_q,w_k,b_k,w_v,b_v,w_o,b_o
  const float4* value4 = (const float4*)d_in[2];
  const float4* wv4 = (const float4*)d_in[7];
  const float* bv = (const float*)d_in[8];
  const float4* wo4 = (const float4*)d_in[9];
  const float* bo = (const float*)d_in[10];

  float4* ws4 = (float4*)d_ws;
  float4* partial4 = ws4 + WSP_PART;
  float* attn = (float*)(ws4 + WSP_ATTN);
  float* fin = (float*)(ws4 + WSP_FIN);

  k_colsum_partial<<<256, 512, 0, stream>>>(value4, partial4);
  k_gemv1<<<256, 256, 0, stream>>>(partial4, wv4, bv, attn);
  k_gemv2<<<256, 256, 0, stream>>>(attn, wo4, bo, fin);
  k_bcast<<<512, 512, 0, stream>>>(fin, (float4*)d_out);
}